// Round 2
// baseline (608.180 us; speedup 1.0000x reference)
//
#include <hip/hip_runtime.h>
#include <hip/hip_bf16.h>

#define D_ 128
#define NQ_ 256
#define NK_ 2048
#define P_TOT (NQ_ * NK_)   // 524288

typedef float f32x4 __attribute__((ext_vector_type(4)));
typedef short bf16x8 __attribute__((ext_vector_type(8)));

__device__ __forceinline__ unsigned short f2bf(float x) {
    union { float f; unsigned u; } v; v.f = x;
    unsigned r = v.u + 0x7FFFu + ((v.u >> 16) & 1u);   // RNE
    return (unsigned short)(r >> 16);
}

// async global->LDS, 16B per lane (wave-uniform LDS base, per-lane global addr)
__device__ __forceinline__ void gload16(const float* g, float* l) {
    __builtin_amdgcn_global_load_lds((const __attribute__((address_space(1))) void*)g,
                                     (__attribute__((address_space(3))) void*)l, 16, 0, 0);
}

// ---------------- init: global-min cell ----------------
__global__ void k_init(unsigned* minw) { *minw = 0xFFFFFFFFu; }

// ---------------- qb[o][n] = b1[o] + sum_c wq[o][c] * x[c][n] ----------------
__global__ __launch_bounds__(256) void k_qb(const float* __restrict__ w1,
                                            const float* __restrict__ x,
                                            const float* __restrict__ b1,
                                            float* __restrict__ qb) {
    int idx = blockIdx.x * 256 + threadIdx.x;
    int o = idx >> 8, n = idx & 255;
    const float* wr = w1 + o * 384;
    float acc = b1[o];
#pragma unroll 4
    for (int c = 0; c < 128; ++c) acc = fmaf(wr[c], x[c * 256 + n], acc);
    qb[o * 256 + n] = acc;
}

// ---------------- kh[o][m] = sum_c wk[o][c] * source[c][m] ----------------
__global__ __launch_bounds__(256) void k_kh(const float* __restrict__ w1,
                                            const float* __restrict__ src,
                                            float* __restrict__ kh) {
    int idx = blockIdx.x * 256 + threadIdx.x;
    int o = idx >> 11, m = idx & 2047;
    const float* wr = w1 + o * 384 + 128;
    float acc = 0.f;
#pragma unroll 4
    for (int c = 0; c < 128; ++c) acc = fmaf(wr[c], src[c * 2048 + m], acc);
    kh[o * 2048 + m] = acc;
}

// ---------------- k_scores helpers ----------------
__device__ __forceinline__ void stage(float* buf, const float* dist, int chunk, int half,
                                      int wid, int lane) {
    const size_t p0 = (size_t)chunk * 256;
    const int c0 = half * 64 + wid * 8;
    const float* g = dist + (size_t)c0 * P_TOT + p0 + lane * 4;
    float* lb = buf + (wid * 8) * 256;
#pragma unroll
    for (int rr = 0; rr < 8; ++rr)
        gload16(g + (size_t)rr * P_TOT, lb + rr * 256);
}

template<int H>
__device__ __forceinline__ void computeHalf(const float* buf, f32x4 (&acc)[2][8],
                                            const bf16x8 (&A)[8][4], int wid, int lg, int c16) {
#pragma unroll
    for (int s = 0; s < 2; ++s) {
        const int pl = wid * 32 + s * 16 + c16;
#pragma unroll
        for (int kt2 = 0; kt2 < 2; ++kt2) {
            const float* rp = buf + (kt2 * 32 + lg * 8) * 256 + pl;
            float tv[8];
#pragma unroll
            for (int b = 0; b < 8; ++b) tv[b] = rp[b * 256];
            union { unsigned d[4]; bf16x8 v; } bb;
#pragma unroll
            for (int i = 0; i < 4; ++i) {
                unsigned r0 = __float_as_uint(tv[2 * i])     + 0x8000u;  // round-half-up
                unsigned r1 = __float_as_uint(tv[2 * i + 1]) + 0x8000u;
                bb.d[i] = __builtin_amdgcn_perm(r1, r0, 0x07060302u);    // high halves
            }
#pragma unroll
            for (int mt = 0; mt < 8; ++mt)
                acc[s][mt] = __builtin_amdgcn_mfma_f32_16x16x32_bf16(
                    A[mt][H * 2 + kt2], bb.v, acc[s][mt], 0, 0, 0);
        }
    }
}

// ---------------- scores (raw) + global min ----------------
// dh = Wd @ dist via bf16 MFMA on LDS-staged f32 tiles; fused epilogue:
// score = b2 + sum_o w2[o]*relu(dh+qb+kh)
__global__ __launch_bounds__(512, 2) void k_scores(
    const float* __restrict__ dist, const float* __restrict__ w1,
    const float* __restrict__ qb, const float* __restrict__ kh,
    const float* __restrict__ w2, const float* __restrict__ b2,
    float* __restrict__ scores, unsigned* __restrict__ minw) {
    __shared__ __align__(16) float lds[2 * 64 * 256];   // 128 KB: two 64c x 256p f32 tiles
    const int tid = threadIdx.x;
    const int l = tid & 63, wid = tid >> 6;
    const int lg = l >> 4, c16 = l & 15;

    // ---- stage Wd (w1 cols 256..384) as bf16 A-fragments into lds[0] region ----
    {
        bf16x8* ldsA = (bf16x8*)lds;
#pragma unroll
        for (int i = 0; i < 4; ++i) {
            int s = tid + i * 512;           // 0..2047 : o = s>>4, octet = s&15
            int o = s >> 4, oct = s & 15;
            const float* g = w1 + o * 384 + 256 + oct * 8;
            float4 f0 = *(const float4*)g;
            float4 f1 = *(const float4*)(g + 4);
            union { bf16x8 v; unsigned short u[8]; } pk;
            pk.u[0] = f2bf(f0.x); pk.u[1] = f2bf(f0.y); pk.u[2] = f2bf(f0.z); pk.u[3] = f2bf(f0.w);
            pk.u[4] = f2bf(f1.x); pk.u[5] = f2bf(f1.y); pk.u[6] = f2bf(f1.z); pk.u[7] = f2bf(f1.w);
            int mt = o >> 4, kt = oct >> 2;
            int lane2 = ((oct & 3) << 4) | (o & 15);
            ldsA[(mt * 4 + kt) * 64 + lane2] = pk.v;
        }
    }
    __syncthreads();
    bf16x8 A[8][4];
    {
        bf16x8* ldsA = (bf16x8*)lds;
#pragma unroll
        for (int mt = 0; mt < 8; ++mt)
#pragma unroll
            for (int kt = 0; kt < 4; ++kt)
                A[mt][kt] = ldsA[(mt * 4 + kt) * 64 + l];
    }
    __syncthreads();   // all A reads done before tile 0 overwrites lds[0]

    f32x4 acc[2][8];
#pragma unroll
    for (int s = 0; s < 2; ++s)
#pragma unroll
        for (int mt = 0; mt < 8; ++mt) acc[s][mt] = (f32x4){0.f, 0.f, 0.f, 0.f};

    const float b2v = b2[0];
    float runmin = 1e30f;
    const int cid0 = blockIdx.x * 8;   // 8 chunks of 256 p per block; grid=256 covers all

    stage(lds, dist, cid0, 0, wid, l);   // prologue prefetch: chunk0 half0 -> buf0

    for (int cc = 0; cc < 8; ++cc) {
        const int chunk = cid0 + cc;

        stage(lds + 16384, dist, chunk, 1, wid, l);     // prefetch half1 -> buf1
        asm volatile("s_waitcnt vmcnt(8)" ::: "memory"); // half0 landed (8 newest stay in flight)
        __builtin_amdgcn_sched_barrier(0);
        __builtin_amdgcn_s_barrier();
        computeHalf<0>(lds, acc, A, wid, lg, c16);
        __builtin_amdgcn_s_barrier();                    // all waves done reading buf0

        if (cc < 7) {
            stage(lds, dist, chunk + 1, 0, wid, l);      // prefetch next chunk half0 -> buf0
            asm volatile("s_waitcnt vmcnt(8)" ::: "memory");
        } else {
            asm volatile("s_waitcnt vmcnt(0)" ::: "memory");
        }
        __builtin_amdgcn_sched_barrier(0);
        __builtin_amdgcn_s_barrier();
        computeHalf<1>(lds + 16384, acc, A, wid, lg, c16);

        // ---- fused epilogue for this chunk (256 scores) ----
        const int n = chunk >> 3;
        const int mbase = (chunk & 7) * 256;
#pragma unroll
        for (int s = 0; s < 2; ++s) {
            const int m = mbase + wid * 32 + s * 16 + c16;
            float sp = 0.f;
#pragma unroll
            for (int mt = 0; mt < 8; ++mt) {
#pragma unroll
                for (int r = 0; r < 4; ++r) {
                    int row = mt * 16 + lg * 4 + r;
                    float t = acc[s][mt][r] + qb[row * 256 + n] + kh[row * 2048 + m];
                    t = fmaxf(t, 0.f);
                    sp = fmaf(w2[row], t, sp);
                }
                acc[s][mt] = (f32x4){0.f, 0.f, 0.f, 0.f};   // reset for next chunk
            }
            sp += __shfl_xor(sp, 16);
            sp += __shfl_xor(sp, 32);
            float score = sp + b2v;
            size_t p = (size_t)chunk * 256 + wid * 32 + s * 16;
            if (l < 16) scores[p + l] = score;
            float mn = score;
            mn = fminf(mn, __shfl_xor(mn, 1));
            mn = fminf(mn, __shfl_xor(mn, 2));
            mn = fminf(mn, __shfl_xor(mn, 4));
            mn = fminf(mn, __shfl_xor(mn, 8));
            runmin = fminf(runmin, mn);
        }
        __builtin_amdgcn_s_barrier();   // all waves done reading buf1 before restage
    }

    union { float f; unsigned u; } e; e.f = runmin;
    unsigned key = (e.u & 0x80000000u) ? ~e.u : (e.u | 0x80000000u);
    if (l == 0) atomicMin(minw, key);
}

// ---------------- mask + softmax + message (fused) ----------------
__global__ __launch_bounds__(256) void k_softmax_msg(
    float* __restrict__ scores, const int* __restrict__ mask,
    const float* __restrict__ src, const unsigned* __restrict__ minw,
    float* __restrict__ msg) {
    int n = blockIdx.x, tid = threadIdx.x;
    __shared__ float sc[2048];
    __shared__ float red[8];

    unsigned key = *minw;
    union { float f; unsigned u; } d;
    d.u = (key & 0x80000000u) ? (key ^ 0x80000000u) : ~key;
    float neg = d.f - 20.f;

    float lmax = -1e30f;
#pragma unroll
    for (int i = 0; i < 8; ++i) {
        int m = tid + i * 256;
        float v = scores[n * 2048 + m];
        if (!mask[n * 2048 + m]) v += neg;
        scores[n * 2048 + m] = v;      // final (masked) scores out
        sc[m] = v;
        lmax = fmaxf(lmax, v);
    }
#pragma unroll
    for (int off = 1; off < 64; off <<= 1) lmax = fmaxf(lmax, __shfl_xor(lmax, off));
    int wv = tid >> 6;
    if ((tid & 63) == 0) red[wv] = lmax;
    __syncthreads();
    float smax = fmaxf(fmaxf(red[0], red[1]), fmaxf(red[2], red[3]));

    float lsum = 0.f;
#pragma unroll
    for (int i = 0; i < 8; ++i) {
        int m = tid + i * 256;
        float e = __expf(sc[m] - smax);
        sc[m] = e;
        lsum += e;
    }
#pragma unroll
    for (int off = 1; off < 64; off <<= 1) lsum += __shfl_xor(lsum, off);
    if ((tid & 63) == 0) red[4 + wv] = lsum;
    __syncthreads();
    float rinv = 1.f / (red[4] + red[5] + red[6] + red[7]);

    int l = tid & 63;
    for (int dd = 0; dd < 32; ++dd) {
        int dch = wv * 32 + dd;
        const float* sr = src + dch * 2048;
        float part = 0.f;
#pragma unroll
        for (int j = 0; j < 32; ++j) {
            int mm = l + j * 64;
            part = fmaf(sc[mm], sr[mm], part);
        }
#pragma unroll
        for (int off = 1; off < 64; off <<= 1) part += __shfl_xor(part, off);
        if (l == 0) msg[dch * 256 + n] = part * rinv;
    }
}

// ---------------- hid[o][n] = relu(b3[o] + sum_c w3[o][c]*cat[c][n]) ----------------
__global__ __launch_bounds__(256) void k_mlp1(const float* __restrict__ x,
                                              const float* __restrict__ msg,
                                              const float* __restrict__ w3,
                                              const float* __restrict__ b3,
                                              float* __restrict__ hid) {
    int o = blockIdx.x, n = threadIdx.x;
    const float* wr = w3 + o * 256;
    float acc = b3[o];
#pragma unroll 4
    for (int c = 0; c < 128; ++c) acc = fmaf(wr[c], x[c * 256 + n], acc);
#pragma unroll 4
    for (int c = 0; c < 128; ++c) acc = fmaf(wr[128 + c], msg[c * 256 + n], acc);
    hid[o * 256 + n] = fmaxf(acc, 0.f);
}

// ---------------- out[o][n] = b4[o] + sum_c w4[o][c]*hid[c][n] ----------------
__global__ __launch_bounds__(256) void k_mlp2(const float* __restrict__ hid,
                                              const float* __restrict__ w4,
                                              const float* __restrict__ b4,
                                              float* __restrict__ out) {
    int o = blockIdx.x, n = threadIdx.x;
    const float* wr = w4 + o * 256;
    float acc = b4[o];
#pragma unroll 4
    for (int c = 0; c < 256; ++c) acc = fmaf(wr[c], hid[c * 256 + n], acc);
    out[o * 256 + n] = acc;
}

extern "C" void kernel_launch(void* const* d_in, const int* in_sizes, int n_in,
                              void* d_out, int out_size, void* d_ws, size_t ws_size,
                              hipStream_t stream) {
    const float* x      = (const float*)d_in[0];
    const float* source = (const float*)d_in[1];
    const float* dist   = (const float*)d_in[2];
    const int*   mask   = (const int*)d_in[3];
    const float* w1     = (const float*)d_in[4];
    const float* b1     = (const float*)d_in[5];
    const float* w2     = (const float*)d_in[6];
    const float* b2     = (const float*)d_in[7];
    const float* w3     = (const float*)d_in[8];
    const float* b3     = (const float*)d_in[9];
    const float* w4     = (const float*)d_in[10];
    const float* b4     = (const float*)d_in[11];

    float* outp    = (float*)d_out;          // 128*256
    float* scoresp = outp + 32768;           // 256*2048 (raw, then masked in-place)

    float* ws   = (float*)d_ws;
    float* qb   = ws;                 // 32768
    float* kh   = ws + 32768;         // 262144
    float* msg  = ws + 294912;        // 32768
    float* hid  = ws + 327680;        // 65536
    unsigned* minw = (unsigned*)(ws + 393216);

    k_init<<<1, 1, 0, stream>>>(minw);
    k_qb<<<128, 256, 0, stream>>>(w1, x, b1, qb);
    k_kh<<<1024, 256, 0, stream>>>(w1, source, kh);
    k_scores<<<256, 512, 0, stream>>>(dist, w1, qb, kh, w2, b2, scoresp, minw);
    k_softmax_msg<<<256, 256, 0, stream>>>(scoresp, mask, source, minw, msg);
    k_mlp1<<<256, 256, 0, stream>>>(x, msg, w3, b3, hid);
    k_mlp2<<<128, 256, 0, stream>>>(hid, w4, b4, outp);
}

// Round 3
// 330.923 us; speedup vs baseline: 1.8378x; 1.8378x over previous
//
#include <hip/hip_runtime.h>
#include <hip/hip_bf16.h>

#define D_ 128
#define NQ_ 256
#define NK_ 2048
#define P_TOT (NQ_ * NK_)   // 524288

typedef float f32x4 __attribute__((ext_vector_type(4)));
typedef short bf16x8 __attribute__((ext_vector_type(8)));

__device__ __forceinline__ unsigned short f2bf(float x) {
    union { float f; unsigned u; } v; v.f = x;
    unsigned r = v.u + 0x7FFFu + ((v.u >> 16) & 1u);   // RNE
    return (unsigned short)(r >> 16);
}

// async global->LDS, 16B per lane (wave-uniform LDS base, per-lane global addr)
__device__ __forceinline__ void gload16(const float* g, float* l) {
    __builtin_amdgcn_global_load_lds((const __attribute__((address_space(1))) void*)g,
                                     (__attribute__((address_space(3))) void*)l, 16, 0, 0);
}

// ---------------- init: global-min cell ----------------
__global__ void k_init(unsigned* minw) { *minw = 0xFFFFFFFFu; }

// ---------------- qb[o][n] = b1[o] + sum_c wq[o][c] * x[c][n] ----------------
__global__ __launch_bounds__(256) void k_qb(const float* __restrict__ w1,
                                            const float* __restrict__ x,
                                            const float* __restrict__ b1,
                                            float* __restrict__ qb) {
    int idx = blockIdx.x * 256 + threadIdx.x;
    int o = idx >> 8, n = idx & 255;
    const float* wr = w1 + o * 384;
    float acc = b1[o];
#pragma unroll 4
    for (int c = 0; c < 128; ++c) acc = fmaf(wr[c], x[c * 256 + n], acc);
    qb[o * 256 + n] = acc;
}

// ---------------- kh[o][m] = sum_c wk[o][c] * source[c][m] ----------------
__global__ __launch_bounds__(256) void k_kh(const float* __restrict__ w1,
                                            const float* __restrict__ src,
                                            float* __restrict__ kh) {
    int idx = blockIdx.x * 256 + threadIdx.x;
    int o = idx >> 11, m = idx & 2047;
    const float* wr = w1 + o * 384 + 128;
    float acc = 0.f;
#pragma unroll 4
    for (int c = 0; c < 128; ++c) acc = fmaf(wr[c], src[c * 2048 + m], acc);
    kh[o * 2048 + m] = acc;
}

// ---------------- scores (raw) + global min ----------------
// Per block: fixed 128-m window (g) x 16-n window (nb). khT/qbT/w2 cached in LDS.
// 8 independent waves, each tri-buffered 16p x 64ch LDS staging, no main-loop barriers.
__global__ __launch_bounds__(512, 2) void k_scores(
    const float* __restrict__ dist, const float* __restrict__ w1,
    const float* __restrict__ qb, const float* __restrict__ kh,
    const float* __restrict__ w2, const float* __restrict__ b2,
    float* __restrict__ scores, unsigned* __restrict__ minw) {
    __shared__ __align__(16) float lds[35072];           // 140288 B
    float* wbufs = lds;                                  // 8 waves * 3 * 1024 f
    unsigned short* khT = (unsigned short*)(lds + 24576); // 128 x 130 bf16 (padded)
    float* qbT = lds + 32896;                            // 16 x 128 f32
    float* w2l = lds + 34944;                            // 128 f32

    const int tid = threadIdx.x;
    const int l = tid & 63, wid = tid >> 6;
    const int lg = l >> 4, c16 = l & 15;
    const int g  = blockIdx.x & 15;    // m-window index (128 m each)
    const int nb = blockIdx.x >> 4;    // n-block index (16 n each)
    const int m0 = g * 128;
    const int n0 = nb * 16;

    // ---- cooperative staging: A-fragments (Wd), khT, qbT, w2 ----
    {
        bf16x8* ldsA = (bf16x8*)lds;   // overlaps wave buffers (freed before main loop)
#pragma unroll
        for (int i = 0; i < 4; ++i) {
            int s = tid + i * 512;     // 0..2047 : o = s>>4, octet = s&15
            int o = s >> 4, oct = s & 15;
            const float* gp = w1 + o * 384 + 256 + oct * 8;
            float4 f0 = *(const float4*)gp;
            float4 f1 = *(const float4*)(gp + 4);
            union { bf16x8 v; unsigned short u[8]; } pk;
            pk.u[0] = f2bf(f0.x); pk.u[1] = f2bf(f0.y); pk.u[2] = f2bf(f0.z); pk.u[3] = f2bf(f0.w);
            pk.u[4] = f2bf(f1.x); pk.u[5] = f2bf(f1.y); pk.u[6] = f2bf(f1.z); pk.u[7] = f2bf(f1.w);
            int mt = o >> 4, kt = oct >> 2;
            int lane2 = ((oct & 3) << 4) | (o & 15);
            ldsA[(mt * 4 + kt) * 64 + lane2] = pk.v;
        }
    }
#pragma unroll
    for (int j = 0; j < 32; ++j) {      // khT[m][o] bf16
        int idx = tid + j * 512;        // 0..16383
        int o = idx >> 7, m = idx & 127;
        khT[m * 130 + o] = f2bf(kh[o * 2048 + m0 + m]);
    }
#pragma unroll
    for (int j = 0; j < 4; ++j) {       // qbT[nl][o] f32
        int idx = tid + j * 512;        // 0..2047
        int o = idx >> 4, nl = idx & 15;
        qbT[nl * 128 + o] = qb[o * 256 + n0 + nl];
    }
    if (tid < 128) w2l[tid] = w2[tid];
    __syncthreads();

    bf16x8 A[8][4];
    {
        bf16x8* ldsA = (bf16x8*)lds;
#pragma unroll
        for (int mt = 0; mt < 8; ++mt)
#pragma unroll
            for (int kt = 0; kt < 4; ++kt)
                A[mt][kt] = ldsA[(mt * 4 + kt) * 64 + l];
    }
    __syncthreads();   // A-region reads done before gload overwrites wave buffers

    // per-lane pre-swizzled global offset (row-rotate perm: LDS row r <- ch with
    // low4(ch) = (r>>1)|((r&1)<<3); gives 2-way-free ds_read banks)
    const int r_ = l >> 2;                              // LDS row within 16-block
    const int chl4 = ((r_ >> 1) & 7) | ((r_ & 1) << 3); // global ch low-4
    const size_t lane_off = (size_t)chl4 * P_TOT + (size_t)((l & 3) * 4);
    // read base: row' = (lg>>1)*16 + (lg&1) (+kt2*32 +2b), col c16
    const int rc = (((lg >> 1) * 16 + (lg & 1)) << 4) + c16;

    float* bufs = wbufs + wid * 3072;
    float* pA = bufs, * pB = bufs + 1024, * pC = bufs + 2048;

    f32x4 acc[8];
#pragma unroll
    for (int mt = 0; mt < 8; ++mt) acc[mt] = (f32x4){0.f, 0.f, 0.f, 0.f};

    const float b2v = b2[0];
    float runmin = 1e30f;
    const int nw0 = n0 + wid * 2;       // wave handles n = nw0, nw0+1

    auto issueH = [&](int h, float* buf) {
        int nl = h >> 4, ms = (h >> 1) & 7, hf = h & 1;
        size_t p0 = (size_t)(nw0 + nl) * 2048 + (size_t)(m0 + ms * 16);
        const float* gb = dist + p0 + lane_off + (size_t)(hf * 64) * P_TOT;
#pragma unroll
        for (int j = 0; j < 4; ++j)
            gload16(gb + (size_t)(j * 16) * P_TOT, buf + j * 256);
    };

    issueH(0, pA);
    issueH(1, pB);

    for (int h = 0; h < 32; ++h) {
        if (h < 30) {
            issueH(h + 2, pC);
            asm volatile("s_waitcnt vmcnt(8)" ::: "memory");
        } else if (h == 30) {
            asm volatile("s_waitcnt vmcnt(4)" ::: "memory");
        } else {
            asm volatile("s_waitcnt vmcnt(0)" ::: "memory");
        }
        __builtin_amdgcn_sched_barrier(0);

        const int hf = h & 1;
#pragma unroll
        for (int kt2 = 0; kt2 < 2; ++kt2) {
            const float* rp = pA + kt2 * 512 + rc;
            float tv[8];
#pragma unroll
            for (int b = 0; b < 8; ++b) tv[b] = rp[b * 32];   // row' += 2 per b
            union { unsigned d[4]; bf16x8 v; } bb;
#pragma unroll
            for (int i = 0; i < 4; ++i) {
                unsigned r0 = __float_as_uint(tv[2 * i])     + 0x8000u;
                unsigned r1 = __float_as_uint(tv[2 * i + 1]) + 0x8000u;
                bb.d[i] = __builtin_amdgcn_perm(r1, r0, 0x07060302u);
            }
#pragma unroll
            for (int mt = 0; mt < 8; ++mt)
                acc[mt] = __builtin_amdgcn_mfma_f32_16x16x32_bf16(
                    A[mt][hf * 2 + kt2], bb.v, acc[mt], 0, 0, 0);
        }

        if (hf) {   // epilogue per 16-p stripe
            int nl = h >> 4, ms = (h >> 1) & 7;
            int n = nw0 + nl;
            const unsigned short* khr = khT + (ms * 16 + c16) * 130;
            const float* qr = qbT + (n - n0) * 128;
            float sp = 0.f;
#pragma unroll
            for (int mt = 0; mt < 8; ++mt) {
                int o = mt * 16 + lg * 4;
                unsigned k01 = *(const unsigned*)(khr + o);
                unsigned k23 = *(const unsigned*)(khr + o + 2);
                float kh0 = __uint_as_float(k01 << 16);
                float kh1 = __uint_as_float(k01 & 0xffff0000u);
                float kh2 = __uint_as_float(k23 << 16);
                float kh3 = __uint_as_float(k23 & 0xffff0000u);
                float4 qv = *(const float4*)(qr + o);
                float4 wv = *(const float4*)(w2l + o);
                float t0 = fmaxf(acc[mt][0] + qv.x + kh0, 0.f);
                float t1 = fmaxf(acc[mt][1] + qv.y + kh1, 0.f);
                float t2 = fmaxf(acc[mt][2] + qv.z + kh2, 0.f);
                float t3 = fmaxf(acc[mt][3] + qv.w + kh3, 0.f);
                sp = fmaf(wv.x, t0, sp); sp = fmaf(wv.y, t1, sp);
                sp = fmaf(wv.z, t2, sp); sp = fmaf(wv.w, t3, sp);
                acc[mt] = (f32x4){0.f, 0.f, 0.f, 0.f};
            }
            sp += __shfl_xor(sp, 16);
            sp += __shfl_xor(sp, 32);
            float score = sp + b2v;
            size_t p0 = (size_t)n * 2048 + (size_t)(m0 + ms * 16);
            if (l < 16) scores[p0 + l] = score;
            float mn = score;
            mn = fminf(mn, __shfl_xor(mn, 1));
            mn = fminf(mn, __shfl_xor(mn, 2));
            mn = fminf(mn, __shfl_xor(mn, 4));
            mn = fminf(mn, __shfl_xor(mn, 8));
            runmin = fminf(runmin, mn);
        }

        float* t = pA; pA = pB; pB = pC; pC = t;
    }

    union { float f; unsigned u; } e; e.f = runmin;
    unsigned key = (e.u & 0x80000000u) ? ~e.u : (e.u | 0x80000000u);
    if (l == 0) atomicMin(minw, key);
}

// ---------------- mask + softmax + message (fused) ----------------
__global__ __launch_bounds__(256) void k_softmax_msg(
    float* __restrict__ scores, const int* __restrict__ mask,
    const float* __restrict__ src, const unsigned* __restrict__ minw,
    float* __restrict__ msg) {
    int n = blockIdx.x, tid = threadIdx.x;
    __shared__ float sc[2048];
    __shared__ float red[8];

    unsigned key = *minw;
    union { float f; unsigned u; } d;
    d.u = (key & 0x80000000u) ? (key ^ 0x80000000u) : ~key;
    float neg = d.f - 20.f;

    float lmax = -1e30f;
#pragma unroll
    for (int i = 0; i < 8; ++i) {
        int m = tid + i * 256;
        float v = scores[n * 2048 + m];
        if (!mask[n * 2048 + m]) v += neg;
        scores[n * 2048 + m] = v;      // final (masked) scores out
        sc[m] = v;
        lmax = fmaxf(lmax, v);
    }
#pragma unroll
    for (int off = 1; off < 64; off <<= 1) lmax = fmaxf(lmax, __shfl_xor(lmax, off));
    int wv = tid >> 6;
    if ((tid & 63) == 0) red[wv] = lmax;
    __syncthreads();
    float smax = fmaxf(fmaxf(red[0], red[1]), fmaxf(red[2], red[3]));

    float lsum = 0.f;
#pragma unroll
    for (int i = 0; i < 8; ++i) {
        int m = tid + i * 256;
        float e = __expf(sc[m] - smax);
        sc[m] = e;
        lsum += e;
    }
#pragma unroll
    for (int off = 1; off < 64; off <<= 1) lsum += __shfl_xor(lsum, off);
    if ((tid & 63) == 0) red[4 + wv] = lsum;
    __syncthreads();
    float rinv = 1.f / (red[4] + red[5] + red[6] + red[7]);

    int l = tid & 63;
    for (int dd = 0; dd < 32; ++dd) {
        int dch = wv * 32 + dd;
        const float* sr = src + dch * 2048;
        float part = 0.f;
#pragma unroll
        for (int j = 0; j < 32; ++j) {
            int mm = l + j * 64;
            part = fmaf(sc[mm], sr[mm], part);
        }
#pragma unroll
        for (int off = 1; off < 64; off <<= 1) part += __shfl_xor(part, off);
        if (l == 0) msg[dch * 256 + n] = part * rinv;
    }
}

// ---------------- hid[o][n] = relu(b3[o] + sum_c w3[o][c]*cat[c][n]) ----------------
__global__ __launch_bounds__(256) void k_mlp1(const float* __restrict__ x,
                                              const float* __restrict__ msg,
                                              const float* __restrict__ w3,
                                              const float* __restrict__ b3,
                                              float* __restrict__ hid) {
    int o = blockIdx.x, n = threadIdx.x;
    const float* wr = w3 + o * 256;
    float acc = b3[o];
#pragma unroll 4
    for (int c = 0; c < 128; ++c) acc = fmaf(wr[c], x[c * 256 + n], acc);
#pragma unroll 4
    for (int c = 0; c < 128; ++c) acc = fmaf(wr[128 + c], msg[c * 256 + n], acc);
    hid[o * 256 + n] = fmaxf(acc, 0.f);
}

// ---------------- out[o][n] = b4[o] + sum_c w4[o][c]*hid[c][n] ----------------
__global__ __launch_bounds__(256) void k_mlp2(const float* __restrict__ hid,
                                              const float* __restrict__ w4,
                                              const float* __restrict__ b4,
                                              float* __restrict__ out) {
    int o = blockIdx.x, n = threadIdx.x;
    const float* wr = w4 + o * 256;
    float acc = b4[o];
#pragma unroll 4
    for (int c = 0; c < 256; ++c) acc = fmaf(wr[c], hid[c * 256 + n], acc);
    out[o * 256 + n] = acc;
}

extern "C" void kernel_launch(void* const* d_in, const int* in_sizes, int n_in,
                              void* d_out, int out_size, void* d_ws, size_t ws_size,
                              hipStream_t stream) {
    const float* x      = (const float*)d_in[0];
    const float* source = (const float*)d_in[1];
    const float* dist   = (const float*)d_in[2];
    const int*   mask   = (const int*)d_in[3];
    const float* w1     = (const float*)d_in[4];
    const float* b1     = (const float*)d_in[5];
    const float* w2     = (const float*)d_in[6];
    const float* b2     = (const float*)d_in[7];
    const float* w3     = (const float*)d_in[8];
    const float* b3     = (const float*)d_in[9];
    const float* w4     = (const float*)d_in[10];
    const float* b4     = (const float*)d_in[11];

    float* outp    = (float*)d_out;          // 128*256
    float* scoresp = outp + 32768;           // 256*2048 (raw, then masked in-place)

    float* ws   = (float*)d_ws;
    float* qb   = ws;                 // 32768
    float* kh   = ws + 32768;         // 262144
    float* msg  = ws + 294912;        // 32768
    float* hid  = ws + 327680;        // 65536
    unsigned* minw = (unsigned*)(ws + 393216);

    k_init<<<1, 1, 0, stream>>>(minw);
    k_qb<<<128, 256, 0, stream>>>(w1, x, b1, qb);
    k_kh<<<1024, 256, 0, stream>>>(w1, source, kh);
    k_scores<<<256, 512, 0, stream>>>(dist, w1, qb, kh, w2, b2, scoresp, minw);
    k_softmax_msg<<<256, 256, 0, stream>>>(scoresp, mask, source, minw, msg);
    k_mlp1<<<256, 256, 0, stream>>>(x, msg, w3, b3, hid);
    k_mlp2<<<128, 256, 0, stream>>>(hid, w4, b4, outp);
}

// Round 4
// 235.665 us; speedup vs baseline: 2.5807x; 1.4042x over previous
//
#include <hip/hip_runtime.h>
#include <hip/hip_bf16.h>

#define D_ 128
#define NQ_ 256
#define NK_ 2048
#define P_TOT (NQ_ * NK_)   // 524288

typedef float f32x4 __attribute__((ext_vector_type(4)));
typedef short bf16x8 __attribute__((ext_vector_type(8)));

__device__ __forceinline__ unsigned short f2bf(float x) {
    union { float f; unsigned u; } v; v.f = x;
    unsigned r = v.u + 0x7FFFu + ((v.u >> 16) & 1u);   // RNE
    return (unsigned short)(r >> 16);
}

// async global->LDS, 16B per lane (wave-uniform LDS base, per-lane global addr)
__device__ __forceinline__ void gload16(const float* g, float* l) {
    __builtin_amdgcn_global_load_lds((const __attribute__((address_space(1))) void*)g,
                                     (__attribute__((address_space(3))) void*)l, 16, 0, 0);
}

// ---------------- init: global-min cell ----------------
__global__ void k_init(unsigned* minw) { *minw = 0xFFFFFFFFu; }

// ---------------- qb[o][n] = b1[o] + sum_c wq[o][c] * x[c][n] ----------------
__global__ __launch_bounds__(256) void k_qb(const float* __restrict__ w1,
                                            const float* __restrict__ x,
                                            const float* __restrict__ b1,
                                            float* __restrict__ qb) {
    int idx = blockIdx.x * 256 + threadIdx.x;
    int o = idx >> 8, n = idx & 255;
    const float* wr = w1 + o * 384;
    float acc = b1[o];
#pragma unroll 4
    for (int c = 0; c < 128; ++c) acc = fmaf(wr[c], x[c * 256 + n], acc);
    qb[o * 256 + n] = acc;
}

// ---------------- kh[o][m] = sum_c wk[o][c] * source[c][m] ----------------
__global__ __launch_bounds__(256) void k_kh(const float* __restrict__ w1,
                                            const float* __restrict__ src,
                                            float* __restrict__ kh) {
    int idx = blockIdx.x * 256 + threadIdx.x;
    int o = idx >> 11, m = idx & 2047;
    const float* wr = w1 + o * 384 + 128;
    float acc = 0.f;
#pragma unroll 4
    for (int c = 0; c < 128; ++c) acc = fmaf(wr[c], src[c * 2048 + m], acc);
    kh[o * 2048 + m] = acc;
}

// ---------------- scores (raw) + global min ----------------
// Per block: fixed 128-m window (g) x 16-n window (nb). khT/qbT/w2 cached in LDS.
// 8 independent waves, tri-buffered 32ch x 32m LDS staging (full 128B lines),
// no main-loop barriers, counted vmcnt waits.
__global__ __launch_bounds__(512, 2) void k_scores(
    const float* __restrict__ dist, const float* __restrict__ w1,
    const float* __restrict__ qb, const float* __restrict__ kh,
    const float* __restrict__ w2, const float* __restrict__ b2,
    float* __restrict__ scores, unsigned* __restrict__ minw) {
    __shared__ __align__(16) float lds[35072];           // 140288 B
    float* wbufs = lds;                                  // 8 waves * 3 * 1024 f
    unsigned short* khT = (unsigned short*)(lds + 24576); // 128 x 130 bf16 (padded)
    float* qbT = lds + 32896;                            // 16 x 128 f32
    float* w2l = lds + 34944;                            // 128 f32

    const int tid = threadIdx.x;
    const int l = tid & 63, wid = tid >> 6;
    const int lg = l >> 4, c16 = l & 15;
    const int g  = blockIdx.x & 15;    // m-window index (128 m each)
    const int nb = blockIdx.x >> 4;    // n-block index (16 n each)
    const int m0 = g * 128;
    const int n0 = nb * 16;

    // ---- cooperative staging: A-fragments (Wd), khT, qbT, w2 ----
    {
        bf16x8* ldsA = (bf16x8*)lds;   // overlaps wave buffers (freed before main loop)
#pragma unroll
        for (int i = 0; i < 4; ++i) {
            int s = tid + i * 512;     // 0..2047 : o = s>>4, octet = s&15
            int o = s >> 4, oct = s & 15;
            const float* gp = w1 + o * 384 + 256 + oct * 8;
            float4 f0 = *(const float4*)gp;
            float4 f1 = *(const float4*)(gp + 4);
            union { bf16x8 v; unsigned short u[8]; } pk;
            pk.u[0] = f2bf(f0.x); pk.u[1] = f2bf(f0.y); pk.u[2] = f2bf(f0.z); pk.u[3] = f2bf(f0.w);
            pk.u[4] = f2bf(f1.x); pk.u[5] = f2bf(f1.y); pk.u[6] = f2bf(f1.z); pk.u[7] = f2bf(f1.w);
            int mt = o >> 4, kt = oct >> 2;
            int lane2 = ((oct & 3) << 4) | (o & 15);     // k(lg,b) = lg*8 + b
            ldsA[(mt * 4 + kt) * 64 + lane2] = pk.v;
        }
    }
#pragma unroll
    for (int j = 0; j < 32; ++j) {      // khT[m][o] bf16
        int idx = tid + j * 512;        // 0..16383
        int o = idx >> 7, m = idx & 127;
        khT[m * 130 + o] = f2bf(kh[o * 2048 + m0 + m]);
    }
#pragma unroll
    for (int j = 0; j < 4; ++j) {       // qbT[nl][o] f32
        int idx = tid + j * 512;        // 0..2047
        int o = idx >> 4, nl = idx & 15;
        qbT[nl * 128 + o] = qb[o * 256 + n0 + nl];
    }
    if (tid < 128) w2l[tid] = w2[tid];
    __syncthreads();

    bf16x8 A[8][4];
    {
        bf16x8* ldsA = (bf16x8*)lds;
#pragma unroll
        for (int mt = 0; mt < 8; ++mt)
#pragma unroll
            for (int kt = 0; kt < 4; ++kt)
                A[mt][kt] = ldsA[(mt * 4 + kt) * 64 + l];
    }
    __syncthreads();   // A-region reads done before gload overwrites wave buffers

    float* bufs = wbufs + wid * 3072;
    float* pA = bufs, * pB = bufs + 1024, * pC = bufs + 2048;

    f32x4 acc[2][8];
#pragma unroll
    for (int s = 0; s < 2; ++s)
#pragma unroll
        for (int mt = 0; mt < 8; ++mt) acc[s][mt] = (f32x4){0.f, 0.f, 0.f, 0.f};

    const float b2v = b2[0];
    float runmin = 1e30f;
    const int nw0 = n0 + wid * 2;       // wave handles n = nw0, nw0+1

    // h: nl = h>>4 (n), ms = (h>>2)&3 (32-m stripe), cq = h&3 (32-ch chunk)
    // LDS tile [32 ch][32 m] f32; staging row = full 128B line.
    auto issueH = [&](int h, float* buf) {
        int nl = h >> 4, ms = (h >> 2) & 3, cq = h & 3;
        size_t pbase = (size_t)(nw0 + nl) * 2048 + (size_t)(m0 + ms * 32);
        const float* gb = dist + (size_t)(cq * 32 + (l >> 3)) * P_TOT + pbase
                               + (size_t)((l & 7) * 4);
#pragma unroll
        for (int j = 0; j < 4; ++j)
            gload16(gb + (size_t)(j * 8) * P_TOT, buf + j * 256);
    };

    issueH(0, pA);
    issueH(1, pB);

    for (int h = 0; h < 32; ++h) {
        if (h < 30) {
            issueH(h + 2, pC);
            asm volatile("s_waitcnt vmcnt(8)" ::: "memory");
        } else if (h == 30) {
            asm volatile("s_waitcnt vmcnt(4)" ::: "memory");
        } else {
            asm volatile("s_waitcnt vmcnt(0)" ::: "memory");
        }
        __builtin_amdgcn_sched_barrier(0);

        const int kt = h & 3;
#pragma unroll
        for (int s = 0; s < 2; ++s) {
            const float* rp = pA + s * 16 + c16;
            float tv[8];
#pragma unroll
            for (int b = 0; b < 8; ++b) tv[b] = rp[(lg * 8 + b) * 32];  // k = lg*8+b
            union { unsigned d[4]; bf16x8 v; } bb;
#pragma unroll
            for (int i = 0; i < 4; ++i) {
                unsigned r0 = __float_as_uint(tv[2 * i])     + 0x8000u;
                unsigned r1 = __float_as_uint(tv[2 * i + 1]) + 0x8000u;
                bb.d[i] = __builtin_amdgcn_perm(r1, r0, 0x07060302u);
            }
#pragma unroll
            for (int mt = 0; mt < 8; ++mt)
                acc[s][mt] = __builtin_amdgcn_mfma_f32_16x16x32_bf16(
                    A[mt][kt], bb.v, acc[s][mt], 0, 0, 0);
        }

        if ((h & 3) == 3) {   // epilogue per (n, 32-m stripe)
            int nl = h >> 4, ms = (h >> 2) & 3;
            int n = nw0 + nl;
            const float* qr = qbT + (n - n0) * 128;
            float sc2[2];
#pragma unroll
            for (int s = 0; s < 2; ++s) {
                const unsigned short* khr = khT + (ms * 32 + s * 16 + c16) * 130;
                float sp = 0.f;
#pragma unroll
                for (int mt = 0; mt < 8; ++mt) {
                    int o = mt * 16 + lg * 4;
                    unsigned k01 = *(const unsigned*)(khr + o);
                    unsigned k23 = *(const unsigned*)(khr + o + 2);
                    float kh0 = __uint_as_float(k01 << 16);
                    float kh1 = __uint_as_float(k01 & 0xffff0000u);
                    float kh2 = __uint_as_float(k23 << 16);
                    float kh3 = __uint_as_float(k23 & 0xffff0000u);
                    float4 qv = *(const float4*)(qr + o);
                    float4 wv = *(const float4*)(w2l + o);
                    float t0 = fmaxf(acc[s][mt][0] + qv.x + kh0, 0.f);
                    float t1 = fmaxf(acc[s][mt][1] + qv.y + kh1, 0.f);
                    float t2 = fmaxf(acc[s][mt][2] + qv.z + kh2, 0.f);
                    float t3 = fmaxf(acc[s][mt][3] + qv.w + kh3, 0.f);
                    sp = fmaf(wv.x, t0, sp); sp = fmaf(wv.y, t1, sp);
                    sp = fmaf(wv.z, t2, sp); sp = fmaf(wv.w, t3, sp);
                    acc[s][mt] = (f32x4){0.f, 0.f, 0.f, 0.f};
                }
                sp += __shfl_xor(sp, 16);
                sp += __shfl_xor(sp, 32);
                sc2[s] = sp + b2v;
            }
            // combined 128B store: lane l<32 writes col l of the 32-m stripe
            float wv = (l < 16) ? sc2[0] : sc2[1];
            if (l < 32) scores[(size_t)n * 2048 + (size_t)(m0 + ms * 32) + l] = wv;
            float mn = fminf(sc2[0], sc2[1]);
            mn = fminf(mn, __shfl_xor(mn, 1));
            mn = fminf(mn, __shfl_xor(mn, 2));
            mn = fminf(mn, __shfl_xor(mn, 4));
            mn = fminf(mn, __shfl_xor(mn, 8));
            runmin = fminf(runmin, mn);
        }

        float* t = pA; pA = pB; pB = pC; pC = t;
    }

    union { float f; unsigned u; } e; e.f = runmin;
    unsigned key = (e.u & 0x80000000u) ? ~e.u : (e.u | 0x80000000u);
    if (l == 0) atomicMin(minw, key);
}

// ---------------- mask + softmax + message (fused) ----------------
__global__ __launch_bounds__(256) void k_softmax_msg(
    float* __restrict__ scores, const int* __restrict__ mask,
    const float* __restrict__ src, const unsigned* __restrict__ minw,
    float* __restrict__ msg) {
    int n = blockIdx.x, tid = threadIdx.x;
    __shared__ float sc[2048];
    __shared__ float red[8];

    unsigned key = *minw;
    union { float f; unsigned u; } d;
    d.u = (key & 0x80000000u) ? (key ^ 0x80000000u) : ~key;
    float neg = d.f - 20.f;

    float lmax = -1e30f;
#pragma unroll
    for (int i = 0; i < 8; ++i) {
        int m = tid + i * 256;
        float v = scores[n * 2048 + m];
        if (!mask[n * 2048 + m]) v += neg;
        scores[n * 2048 + m] = v;      // final (masked) scores out
        sc[m] = v;
        lmax = fmaxf(lmax, v);
    }
#pragma unroll
    for (int off = 1; off < 64; off <<= 1) lmax = fmaxf(lmax, __shfl_xor(lmax, off));
    int wv = tid >> 6;
    if ((tid & 63) == 0) red[wv] = lmax;
    __syncthreads();
    float smax = fmaxf(fmaxf(red[0], red[1]), fmaxf(red[2], red[3]));

    float lsum = 0.f;
#pragma unroll
    for (int i = 0; i < 8; ++i) {
        int m = tid + i * 256;
        float e = __expf(sc[m] - smax);
        sc[m] = e;
        lsum += e;
    }
#pragma unroll
    for (int off = 1; off < 64; off <<= 1) lsum += __shfl_xor(lsum, off);
    if ((tid & 63) == 0) red[4 + wv] = lsum;
    __syncthreads();
    float rinv = 1.f / (red[4] + red[5] + red[6] + red[7]);

    int l = tid & 63;
    for (int dd = 0; dd < 32; ++dd) {
        int dch = wv * 32 + dd;
        const float* sr = src + dch * 2048;
        float part = 0.f;
#pragma unroll
        for (int j = 0; j < 32; ++j) {
            int mm = l + j * 64;
            part = fmaf(sc[mm], sr[mm], part);
        }
#pragma unroll
        for (int off = 1; off < 64; off <<= 1) part += __shfl_xor(part, off);
        if (l == 0) msg[dch * 256 + n] = part * rinv;
    }
}

// ---------------- hid[o][n] = relu(b3[o] + sum_c w3[o][c]*cat[c][n]) ----------------
__global__ __launch_bounds__(256) void k_mlp1(const float* __restrict__ x,
                                              const float* __restrict__ msg,
                                              const float* __restrict__ w3,
                                              const float* __restrict__ b3,
                                              float* __restrict__ hid) {
    int o = blockIdx.x, n = threadIdx.x;
    const float* wr = w3 + o * 256;
    float acc = b3[o];
#pragma unroll 4
    for (int c = 0; c < 128; ++c) acc = fmaf(wr[c], x[c * 256 + n], acc);
#pragma unroll 4
    for (int c = 0; c < 128; ++c) acc = fmaf(wr[128 + c], msg[c * 256 + n], acc);
    hid[o * 256 + n] = fmaxf(acc, 0.f);
}

// ---------------- out[o][n] = b4[o] + sum_c w4[o][c]*hid[c][n] ----------------
__global__ __launch_bounds__(256) void k_mlp2(const float* __restrict__ hid,
                                              const float* __restrict__ w4,
                                              const float* __restrict__ b4,
                                              float* __restrict__ out) {
    int o = blockIdx.x, n = threadIdx.x;
    const float* wr = w4 + o * 256;
    float acc = b4[o];
#pragma unroll 4
    for (int c = 0; c < 256; ++c) acc = fmaf(wr[c], hid[c * 256 + n], acc);
    out[o * 256 + n] = acc;
}

extern "C" void kernel_launch(void* const* d_in, const int* in_sizes, int n_in,
                              void* d_out, int out_size, void* d_ws, size_t ws_size,
                              hipStream_t stream) {
    const float* x      = (const float*)d_in[0];
    const float* source = (const float*)d_in[1];
    const float* dist   = (const float*)d_in[2];
    const int*   mask   = (const int*)d_in[3];
    const float* w1     = (const float*)d_in[4];
    const float* b1     = (const float*)d_in[5];
    const float* w2     = (const float*)d_in[6];
    const float* b2     = (const float*)d_in[7];
    const float* w3     = (const float*)d_in[8];
    const float* b3     = (const float*)d_in[9];
    const float* w4     = (const float*)d_in[10];
    const float* b4     = (const float*)d_in[11];

    float* outp    = (float*)d_out;          // 128*256
    float* scoresp = outp + 32768;           // 256*2048 (raw, then masked in-place)

    float* ws   = (float*)d_ws;
    float* qb   = ws;                 // 32768
    float* kh   = ws + 32768;         // 262144
    float* msg  = ws + 294912;        // 32768
    float* hid  = ws + 327680;        // 65536
    unsigned* minw = (unsigned*)(ws + 393216);

    k_init<<<1, 1, 0, stream>>>(minw);
    k_qb<<<128, 256, 0, stream>>>(w1, x, b1, qb);
    k_kh<<<1024, 256, 0, stream>>>(w1, source, kh);
    k_scores<<<256, 512, 0, stream>>>(dist, w1, qb, kh, w2, b2, scoresp, minw);
    k_softmax_msg<<<256, 256, 0, stream>>>(scoresp, mask, source, minw, msg);
    k_mlp1<<<256, 256, 0, stream>>>(x, msg, w3, b3, hid);
    k_mlp2<<<128, 256, 0, stream>>>(hid, w4, b4, outp);
}

// Round 5
// 168.462 us; speedup vs baseline: 3.6102x; 1.3989x over previous
//
#include <hip/hip_runtime.h>
#include <hip/hip_bf16.h>

#define D_ 128
#define NQ_ 256
#define NK_ 2048
#define P_TOT (NQ_ * NK_)   // 524288

typedef float f32x4 __attribute__((ext_vector_type(4)));
typedef short bf16x8 __attribute__((ext_vector_type(8)));

__device__ __forceinline__ unsigned short f2bf(float x) {
    union { float f; unsigned u; } v; v.f = x;
    unsigned r = v.u + 0x7FFFu + ((v.u >> 16) & 1u);   // RNE
    return (unsigned short)(r >> 16);
}

// async global->LDS, 16B per lane (wave-uniform LDS base, per-lane global addr)
__device__ __forceinline__ void gload16(const float* g, float* l) {
    __builtin_amdgcn_global_load_lds((const __attribute__((address_space(1))) void*)g,
                                     (__attribute__((address_space(3))) void*)l, 16, 0, 0);
}

// ---------------- init: global-min cell ----------------
__global__ void k_init(unsigned* minw) { *minw = 0xFFFFFFFFu; }

// ---------------- qb[o][n] = b1[o] + sum_c wq[o][c] * x[c][n] ----------------
__global__ __launch_bounds__(256) void k_qb(const float* __restrict__ w1,
                                            const float* __restrict__ x,
                                            const float* __restrict__ b1,
                                            float* __restrict__ qb) {
    int idx = blockIdx.x * 256 + threadIdx.x;
    int o = idx >> 8, n = idx & 255;
    const float* wr = w1 + o * 384;
    float acc = b1[o];
#pragma unroll 4
    for (int c = 0; c < 128; ++c) acc = fmaf(wr[c], x[c * 256 + n], acc);
    qb[o * 256 + n] = acc;
}

// ---------------- kh[o][m] = sum_c wk[o][c] * source[c][m] ----------------
__global__ __launch_bounds__(256) void k_kh(const float* __restrict__ w1,
                                            const float* __restrict__ src,
                                            float* __restrict__ kh) {
    int idx = blockIdx.x * 256 + threadIdx.x;
    int o = idx >> 11, m = idx & 2047;
    const float* wr = w1 + o * 384 + 128;
    float acc = 0.f;
#pragma unroll 4
    for (int c = 0; c < 128; ++c) acc = fmaf(wr[c], src[c * 2048 + m], acc);
    kh[o * 2048 + m] = acc;
}

// ---------------- scores (raw) + global min ----------------
// Per block: 256-m window (mb of 8) x 8-n window (nb of 32). Tile = one n's
// [32 ch][256 m] f32 (32 KB), cooperatively staged with FULL 1KB rows via
// global_load_lds, double-buffered, counted vmcnt(4). 64B row-rotation
// (both-sides XOR swizzle) makes fragment ds_reads 2-way (free).
__global__ __launch_bounds__(512, 2) void k_scores(
    const float* __restrict__ dist, const float* __restrict__ w1,
    const float* __restrict__ qb, const float* __restrict__ kh,
    const float* __restrict__ w2, const float* __restrict__ b2,
    float* __restrict__ scores, unsigned* __restrict__ minw) {
    __shared__ __align__(16) float lds[34176];            // 136704 B
    float* buf0 = lds;                                    // [32][256] f32
    float* buf1 = lds + 8192;
    unsigned short* khT = (unsigned short*)(lds + 16384); // [256][130] bf16
    float* qbT = lds + 33024;                             // [8][128] f32
    float* w2l = lds + 34048;                             // 128 f32

    const int tid = threadIdx.x;
    const int l = tid & 63, wid = tid >> 6;
    const int lg = l >> 4, c16 = l & 15;
    const int mb = blockIdx.x & 7, nb = blockIdx.x >> 3;
    const int m0 = mb * 256, n0 = nb * 8;

    // ---- cooperative staging: A-fragments (Wd) into buf area, khT, qbT, w2 ----
    {
        bf16x8* ldsA = (bf16x8*)lds;   // 32 KB, freed before main loop
#pragma unroll
        for (int i = 0; i < 4; ++i) {
            int s = tid + i * 512;     // 0..2047 : o = s>>4, octet = s&15
            int o = s >> 4, oct = s & 15;
            const float* gp = w1 + o * 384 + 256 + oct * 8;
            float4 f0 = *(const float4*)gp;
            float4 f1 = *(const float4*)(gp + 4);
            union { bf16x8 v; unsigned short u[8]; } pk;
            pk.u[0] = f2bf(f0.x); pk.u[1] = f2bf(f0.y); pk.u[2] = f2bf(f0.z); pk.u[3] = f2bf(f0.w);
            pk.u[4] = f2bf(f1.x); pk.u[5] = f2bf(f1.y); pk.u[6] = f2bf(f1.z); pk.u[7] = f2bf(f1.w);
            int mt = o >> 4, kt = oct >> 2;
            int lane2 = ((oct & 3) << 4) | (o & 15);     // k(lg,b) = lg*8 + b
            ldsA[(mt * 4 + kt) * 64 + lane2] = pk.v;
        }
    }
#pragma unroll
    for (int jj = 0; jj < 16; ++jj) {   // khT[m][o] bf16, float4 global reads
        int e = tid + jj * 512;         // 0..8191
        int o = e >> 6, mq = e & 63;
        float4 f = *(const float4*)&kh[o * 2048 + m0 + mq * 4];
        khT[(mq * 4 + 0) * 130 + o] = f2bf(f.x);
        khT[(mq * 4 + 1) * 130 + o] = f2bf(f.y);
        khT[(mq * 4 + 2) * 130 + o] = f2bf(f.z);
        khT[(mq * 4 + 3) * 130 + o] = f2bf(f.w);
    }
#pragma unroll
    for (int jj = 0; jj < 2; ++jj) {    // qbT[nl][o] f32
        int e = tid + jj * 512;         // 0..1023
        int o = e >> 3, nl2 = e & 7;
        qbT[nl2 * 128 + o] = qb[o * 256 + n0 + nl2];
    }
    if (tid < 128) w2l[tid] = w2[tid];
    __syncthreads();

    bf16x8 A[8][4];
    {
        bf16x8* ldsA = (bf16x8*)lds;
#pragma unroll
        for (int mt = 0; mt < 8; ++mt)
#pragma unroll
            for (int kt = 0; kt < 4; ++kt)
                A[mt][kt] = ldsA[(mt * 4 + kt) * 64 + l];
    }
    __syncthreads();   // A area freed -> becomes tile buffers

    f32x4 acc[2][8];
#pragma unroll
    for (int s = 0; s < 2; ++s)
#pragma unroll
        for (int mt = 0; mt < 8; ++mt) acc[s][mt] = (f32x4){0.f, 0.f, 0.f, 0.f};

    const float b2v = b2[0];
    float runmin = 1e30f;

    // stage tile (n_l, cq): wave stages rows wid*4..wid*4+3, each one full 1KB
    // row, 16B-groups rotated by x=((row>>3)&1)<<2 (pre-swizzled global src)
    auto issueT = [&](int n_l, int cq, float* buf) {
        const float* basep = dist + (size_t)(n0 + n_l) * 2048 + (size_t)m0;
#pragma unroll
        for (int j = 0; j < 4; ++j) {
            int row = wid * 4 + j;
            int x = ((row >> 3) & 1) << 2;
            gload16(basep + (size_t)(cq * 32 + row) * (size_t)P_TOT + ((l ^ x) << 2),
                    buf + row * 256);
        }
    };

    auto epi = [&](int nl) {
        const float* qr = qbT + nl * 128;
        float sc2[2];
#pragma unroll
        for (int s = 0; s < 2; ++s) {
            const unsigned short* khr = khT + (wid * 32 + s * 16 + c16) * 130;
            float sp = 0.f;
#pragma unroll
            for (int mt = 0; mt < 8; ++mt) {
                int o = mt * 16 + lg * 4;
                unsigned k01 = *(const unsigned*)(khr + o);
                unsigned k23 = *(const unsigned*)(khr + o + 2);
                float kh0 = __uint_as_float(k01 << 16);
                float kh1 = __uint_as_float(k01 & 0xffff0000u);
                float kh2 = __uint_as_float(k23 << 16);
                float kh3 = __uint_as_float(k23 & 0xffff0000u);
                float4 qv = *(const float4*)(qr + o);
                float4 wv = *(const float4*)(w2l + o);
                float t0 = fmaxf(acc[s][mt][0] + qv.x + kh0, 0.f);
                float t1 = fmaxf(acc[s][mt][1] + qv.y + kh1, 0.f);
                float t2 = fmaxf(acc[s][mt][2] + qv.z + kh2, 0.f);
                float t3 = fmaxf(acc[s][mt][3] + qv.w + kh3, 0.f);
                sp = fmaf(wv.x, t0, sp); sp = fmaf(wv.y, t1, sp);
                sp = fmaf(wv.z, t2, sp); sp = fmaf(wv.w, t3, sp);
                acc[s][mt] = (f32x4){0.f, 0.f, 0.f, 0.f};
            }
            sp += __shfl_xor(sp, 16);
            sp += __shfl_xor(sp, 32);
            sc2[s] = sp + b2v;
        }
        float wv = (l < 16) ? sc2[0] : sc2[1];
        if (l < 32) scores[(size_t)(n0 + nl) * 2048 + (size_t)(m0 + wid * 32) + l] = wv;
        float mn = fminf(sc2[0], sc2[1]);
        mn = fminf(mn, __shfl_xor(mn, 1));
        mn = fminf(mn, __shfl_xor(mn, 2));
        mn = fminf(mn, __shfl_xor(mn, 4));
        mn = fminf(mn, __shfl_xor(mn, 8));
        runmin = fminf(runmin, mn);
    };

    issueT(0, 0, buf0);
    issueT(0, 1, buf1);

    // STEP(CQ): vmcnt -> barrier -> compute (+epi) -> barrier -> issue t+2
#define STEP(CQ, NL, DO_ISSUE, LAST)                                             \
    {                                                                            \
        float* cur = ((CQ) & 1) ? buf1 : buf0;                                   \
        if (LAST) { asm volatile("s_waitcnt vmcnt(0)" ::: "memory"); }           \
        else      { asm volatile("s_waitcnt vmcnt(4)" ::: "memory"); }           \
        __builtin_amdgcn_sched_barrier(0);                                       \
        __builtin_amdgcn_s_barrier();                                            \
        _Pragma("unroll")                                                        \
        for (int s = 0; s < 2; ++s) {                                            \
            const int grpx = (wid * 8 + s * 4 + (c16 >> 2)) ^ ((lg & 1) << 2);   \
            const float* rp = cur + lg * 2048 + grpx * 4 + (c16 & 3);            \
            float tv[8];                                                         \
            _Pragma("unroll")                                                    \
            for (int b = 0; b < 8; ++b) tv[b] = rp[b * 256];                     \
            union { unsigned d[4]; bf16x8 v; } bb;                               \
            _Pragma("unroll")                                                    \
            for (int i = 0; i < 4; ++i) {                                        \
                unsigned r0 = __float_as_uint(tv[2 * i])     + 0x8000u;          \
                unsigned r1 = __float_as_uint(tv[2 * i + 1]) + 0x8000u;          \
                bb.d[i] = __builtin_amdgcn_perm(r1, r0, 0x07060302u);            \
            }                                                                    \
            _Pragma("unroll")                                                    \
            for (int mt = 0; mt < 8; ++mt)                                       \
                acc[s][mt] = __builtin_amdgcn_mfma_f32_16x16x32_bf16(            \
                    A[mt][(CQ)], bb.v, acc[s][mt], 0, 0, 0);                     \
        }                                                                        \
        if ((CQ) == 3) epi(NL);                                                  \
        __builtin_amdgcn_s_barrier();                                            \
        if (DO_ISSUE) issueT((NL) + ((CQ) >= 2 ? 1 : 0), ((CQ) + 2) & 3, cur);   \
    }

    for (int nl = 0; nl < 7; ++nl) {
        STEP(0, nl, true, false)
        STEP(1, nl, true, false)
        STEP(2, nl, true, false)
        STEP(3, nl, true, false)
    }
    STEP(0, 7, true,  false)   // t=28, issue t=30
    STEP(1, 7, true,  false)   // t=29, issue t=31
    STEP(2, 7, false, false)   // t=30
    STEP(3, 7, false, true)    // t=31
#undef STEP

    union { float f; unsigned u; } e; e.f = runmin;
    unsigned key = (e.u & 0x80000000u) ? ~e.u : (e.u | 0x80000000u);
    if (l == 0) atomicMin(minw, key);
}

// ---------------- mask + softmax + message (fused) ----------------
__global__ __launch_bounds__(256) void k_softmax_msg(
    float* __restrict__ scores, const int* __restrict__ mask,
    const float* __restrict__ src, const unsigned* __restrict__ minw,
    float* __restrict__ msg) {
    int n = blockIdx.x, tid = threadIdx.x;
    __shared__ float sc[2048];
    __shared__ float red[8];

    unsigned key = *minw;
    union { float f; unsigned u; } d;
    d.u = (key & 0x80000000u) ? (key ^ 0x80000000u) : ~key;
    float neg = d.f - 20.f;

    float lmax = -1e30f;
#pragma unroll
    for (int i = 0; i < 8; ++i) {
        int m = tid + i * 256;
        float v = scores[n * 2048 + m];
        if (!mask[n * 2048 + m]) v += neg;
        scores[n * 2048 + m] = v;      // final (masked) scores out
        sc[m] = v;
        lmax = fmaxf(lmax, v);
    }
#pragma unroll
    for (int off = 1; off < 64; off <<= 1) lmax = fmaxf(lmax, __shfl_xor(lmax, off));
    int wv = tid >> 6;
    if ((tid & 63) == 0) red[wv] = lmax;
    __syncthreads();
    float smax = fmaxf(fmaxf(red[0], red[1]), fmaxf(red[2], red[3]));

    float lsum = 0.f;
#pragma unroll
    for (int i = 0; i < 8; ++i) {
        int m = tid + i * 256;
        float e = __expf(sc[m] - smax);
        sc[m] = e;
        lsum += e;
    }
#pragma unroll
    for (int off = 1; off < 64; off <<= 1) lsum += __shfl_xor(lsum, off);
    if ((tid & 63) == 0) red[4 + wv] = lsum;
    __syncthreads();
    float rinv = 1.f / (red[4] + red[5] + red[6] + red[7]);

    int l = tid & 63;
    for (int dd = 0; dd < 32; ++dd) {
        int dch = wv * 32 + dd;
        const float* sr = src + dch * 2048;
        float part = 0.f;
#pragma unroll
        for (int j = 0; j < 32; ++j) {
            int mm = l + j * 64;
            part = fmaf(sc[mm], sr[mm], part);
        }
#pragma unroll
        for (int off = 1; off < 64; off <<= 1) part += __shfl_xor(part, off);
        if (l == 0) msg[dch * 256 + n] = part * rinv;
    }
}

// ---------------- hid[o][n] = relu(b3[o] + sum_c w3[o][c]*cat[c][n]) ----------------
__global__ __launch_bounds__(256) void k_mlp1(const float* __restrict__ x,
                                              const float* __restrict__ msg,
                                              const float* __restrict__ w3,
                                              const float* __restrict__ b3,
                                              float* __restrict__ hid) {
    int o = blockIdx.x, n = threadIdx.x;
    const float* wr = w3 + o * 256;
    float acc = b3[o];
#pragma unroll 4
    for (int c = 0; c < 128; ++c) acc = fmaf(wr[c], x[c * 256 + n], acc);
#pragma unroll 4
    for (int c = 0; c < 128; ++c) acc = fmaf(wr[128 + c], msg[c * 256 + n], acc);
    hid[o * 256 + n] = fmaxf(acc, 0.f);
}

// ---------------- out[o][n] = b4[o] + sum_c w4[o][c]*hid[c][n] ----------------
__global__ __launch_bounds__(256) void k_mlp2(const float* __restrict__ hid,
                                              const float* __restrict__ w4,
                                              const float* __restrict__ b4,
                                              float* __restrict__ out) {
    int o = blockIdx.x, n = threadIdx.x;
    const float* wr = w4 + o * 256;
    float acc = b4[o];
#pragma unroll 4
    for (int c = 0; c < 256; ++c) acc = fmaf(wr[c], hid[c * 256 + n], acc);
    out[o * 256 + n] = acc;
}

extern "C" void kernel_launch(void* const* d_in, const int* in_sizes, int n_in,
                              void* d_out, int out_size, void* d_ws, size_t ws_size,
                              hipStream_t stream) {
    const float* x      = (const float*)d_in[0];
    const float* source = (const float*)d_in[1];
    const float* dist   = (const float*)d_in[2];
    const int*   mask   = (const int*)d_in[3];
    const float* w1     = (const float*)d_in[4];
    const float* b1     = (const float*)d_in[5];
    const float* w2     = (const float*)d_in[6];
    const float* b2     = (const float*)d_in[7];
    const float* w3     = (const float*)d_in[8];
    const float* b3     = (const float*)d_in[9];
    const float* w4     = (const float*)d_in[10];
    const float* b4     = (const float*)d_in[11];

    float* outp    = (float*)d_out;          // 128*256
    float* scoresp = outp + 32768;           // 256*2048 (raw, then masked in-place)

    float* ws   = (float*)d_ws;
    float* qb   = ws;                 // 32768
    float* kh   = ws + 32768;         // 262144
    float* msg  = ws + 294912;        // 32768
    float* hid  = ws + 327680;        // 65536
    unsigned* minw = (unsigned*)(ws + 393216);

    k_init<<<1, 1, 0, stream>>>(minw);
    k_qb<<<128, 256, 0, stream>>>(w1, x, b1, qb);
    k_kh<<<1024, 256, 0, stream>>>(w1, source, kh);
    k_scores<<<256, 512, 0, stream>>>(dist, w1, qb, kh, w2, b2, scoresp, minw);
    k_softmax_msg<<<256, 256, 0, stream>>>(scoresp, mask, source, minw, msg);
    k_mlp1<<<256, 256, 0, stream>>>(x, msg, w3, b3, hid);
    k_mlp2<<<128, 256, 0, stream>>>(hid, w4, b4, outp);
}

// Round 6
// 135.792 us; speedup vs baseline: 4.4788x; 1.2406x over previous
//
#include <hip/hip_runtime.h>
#include <hip/hip_bf16.h>

#define D_ 128
#define NQ_ 256
#define NK_ 2048
#define P_TOT (NQ_ * NK_)   // 524288

typedef float f32x4 __attribute__((ext_vector_type(4)));
typedef short bf16x8 __attribute__((ext_vector_type(8)));

__device__ __forceinline__ unsigned short f2bf(float x) {
    union { float f; unsigned u; } v; v.f = x;
    unsigned r = v.u + 0x7FFFu + ((v.u >> 16) & 1u);   // RNE
    return (unsigned short)(r >> 16);
}

// async global->LDS, 16B per lane (wave-uniform LDS base, per-lane global addr)
__device__ __forceinline__ void gload16(const float* g, float* l) {
    __builtin_amdgcn_global_load_lds((const __attribute__((address_space(1))) void*)g,
                                     (__attribute__((address_space(3))) void*)l, 16, 0, 0);
}

// ---------------- prep: minw init + qb + kh + p1 ----------------
// blocks 0..127: qb[o][n]  (o=b, n=t)
// blocks 128..1151: kh[o][m]
// blocks 1152..1407: p1[o][n] = b3[o] + sum_{c<128} w3[o][c]*x[c][n]
__global__ __launch_bounds__(256) void k_prep(
    const float* __restrict__ w1, const float* __restrict__ x,
    const float* __restrict__ b1, const float* __restrict__ src,
    const float* __restrict__ w3, const float* __restrict__ b3,
    float* __restrict__ qb, float* __restrict__ kh, float* __restrict__ p1,
    unsigned* __restrict__ minw) {
    int b = blockIdx.x, t = threadIdx.x;
    if (b == 0 && t == 0) *minw = 0xFFFFFFFFu;
    if (b < 128) {
        int o = b, n = t;
        const float* wr = w1 + o * 384;
        float acc = b1[o];
#pragma unroll 4
        for (int c = 0; c < 128; ++c) acc = fmaf(wr[c], x[c * 256 + n], acc);
        qb[o * 256 + n] = acc;
    } else if (b < 1152) {
        int idx = (b - 128) * 256 + t;
        int o = idx >> 11, m = idx & 2047;
        const float* wr = w1 + o * 384 + 128;
        float acc = 0.f;
#pragma unroll 4
        for (int c = 0; c < 128; ++c) acc = fmaf(wr[c], src[c * 2048 + m], acc);
        kh[o * 2048 + m] = acc;
    } else {
        int o = b - 1152, n = t;
        const float* wr = w3 + o * 256;
        float acc = b3[o];
#pragma unroll 4
        for (int c = 0; c < 128; ++c) acc = fmaf(wr[c], x[c * 256 + n], acc);
        p1[o * 256 + n] = acc;
    }
}

// ---------------- scores (raw) + global min ----------------
// UNCHANGED from round 5 (known-good): per block 256-m x 8-n window, tile =
// one n's [32 ch][256 m] f32 staged with full 1KB rows via global_load_lds,
// double-buffered, counted vmcnt(4), both-sides 64B rotation swizzle.
__global__ __launch_bounds__(512, 2) void k_scores(
    const float* __restrict__ dist, const float* __restrict__ w1,
    const float* __restrict__ qb, const float* __restrict__ kh,
    const float* __restrict__ w2, const float* __restrict__ b2,
    float* __restrict__ scores, unsigned* __restrict__ minw) {
    __shared__ __align__(16) float lds[34176];            // 136704 B
    float* buf0 = lds;                                    // [32][256] f32
    float* buf1 = lds + 8192;
    unsigned short* khT = (unsigned short*)(lds + 16384); // [256][130] bf16
    float* qbT = lds + 33024;                             // [8][128] f32
    float* w2l = lds + 34048;                             // 128 f32

    const int tid = threadIdx.x;
    const int l = tid & 63, wid = tid >> 6;
    const int lg = l >> 4, c16 = l & 15;
    const int mb = blockIdx.x & 7, nb = blockIdx.x >> 3;
    const int m0 = mb * 256, n0 = nb * 8;

    {
        bf16x8* ldsA = (bf16x8*)lds;   // 32 KB, freed before main loop
#pragma unroll
        for (int i = 0; i < 4; ++i) {
            int s = tid + i * 512;
            int o = s >> 4, oct = s & 15;
            const float* gp = w1 + o * 384 + 256 + oct * 8;
            float4 f0 = *(const float4*)gp;
            float4 f1 = *(const float4*)(gp + 4);
            union { bf16x8 v; unsigned short u[8]; } pk;
            pk.u[0] = f2bf(f0.x); pk.u[1] = f2bf(f0.y); pk.u[2] = f2bf(f0.z); pk.u[3] = f2bf(f0.w);
            pk.u[4] = f2bf(f1.x); pk.u[5] = f2bf(f1.y); pk.u[6] = f2bf(f1.z); pk.u[7] = f2bf(f1.w);
            int mt = o >> 4, kt = oct >> 2;
            int lane2 = ((oct & 3) << 4) | (o & 15);
            ldsA[(mt * 4 + kt) * 64 + lane2] = pk.v;
        }
    }
#pragma unroll
    for (int jj = 0; jj < 16; ++jj) {
        int e = tid + jj * 512;
        int o = e >> 6, mq = e & 63;
        float4 f = *(const float4*)&kh[o * 2048 + m0 + mq * 4];
        khT[(mq * 4 + 0) * 130 + o] = f2bf(f.x);
        khT[(mq * 4 + 1) * 130 + o] = f2bf(f.y);
        khT[(mq * 4 + 2) * 130 + o] = f2bf(f.z);
        khT[(mq * 4 + 3) * 130 + o] = f2bf(f.w);
    }
#pragma unroll
    for (int jj = 0; jj < 2; ++jj) {
        int e = tid + jj * 512;
        int o = e >> 3, nl2 = e & 7;
        qbT[nl2 * 128 + o] = qb[o * 256 + n0 + nl2];
    }
    if (tid < 128) w2l[tid] = w2[tid];
    __syncthreads();

    bf16x8 A[8][4];
    {
        bf16x8* ldsA = (bf16x8*)lds;
#pragma unroll
        for (int mt = 0; mt < 8; ++mt)
#pragma unroll
            for (int kt = 0; kt < 4; ++kt)
                A[mt][kt] = ldsA[(mt * 4 + kt) * 64 + l];
    }
    __syncthreads();

    f32x4 acc[2][8];
#pragma unroll
    for (int s = 0; s < 2; ++s)
#pragma unroll
        for (int mt = 0; mt < 8; ++mt) acc[s][mt] = (f32x4){0.f, 0.f, 0.f, 0.f};

    const float b2v = b2[0];
    float runmin = 1e30f;

    auto issueT = [&](int n_l, int cq, float* buf) {
        const float* basep = dist + (size_t)(n0 + n_l) * 2048 + (size_t)m0;
#pragma unroll
        for (int j = 0; j < 4; ++j) {
            int row = wid * 4 + j;
            int x = ((row >> 3) & 1) << 2;
            gload16(basep + (size_t)(cq * 32 + row) * (size_t)P_TOT + ((l ^ x) << 2),
                    buf + row * 256);
        }
    };

    auto epi = [&](int nl) {
        const float* qr = qbT + nl * 128;
        float sc2[2];
#pragma unroll
        for (int s = 0; s < 2; ++s) {
            const unsigned short* khr = khT + (wid * 32 + s * 16 + c16) * 130;
            float sp = 0.f;
#pragma unroll
            for (int mt = 0; mt < 8; ++mt) {
                int o = mt * 16 + lg * 4;
                unsigned k01 = *(const unsigned*)(khr + o);
                unsigned k23 = *(const unsigned*)(khr + o + 2);
                float kh0 = __uint_as_float(k01 << 16);
                float kh1 = __uint_as_float(k01 & 0xffff0000u);
                float kh2 = __uint_as_float(k23 << 16);
                float kh3 = __uint_as_float(k23 & 0xffff0000u);
                float4 qv = *(const float4*)(qr + o);
                float4 wv = *(const float4*)(w2l + o);
                float t0 = fmaxf(acc[s][mt][0] + qv.x + kh0, 0.f);
                float t1 = fmaxf(acc[s][mt][1] + qv.y + kh1, 0.f);
                float t2 = fmaxf(acc[s][mt][2] + qv.z + kh2, 0.f);
                float t3 = fmaxf(acc[s][mt][3] + qv.w + kh3, 0.f);
                sp = fmaf(wv.x, t0, sp); sp = fmaf(wv.y, t1, sp);
                sp = fmaf(wv.z, t2, sp); sp = fmaf(wv.w, t3, sp);
                acc[s][mt] = (f32x4){0.f, 0.f, 0.f, 0.f};
            }
            sp += __shfl_xor(sp, 16);
            sp += __shfl_xor(sp, 32);
            sc2[s] = sp + b2v;
        }
        float wv = (l < 16) ? sc2[0] : sc2[1];
        if (l < 32) scores[(size_t)(n0 + nl) * 2048 + (size_t)(m0 + wid * 32) + l] = wv;
        float mn = fminf(sc2[0], sc2[1]);
        mn = fminf(mn, __shfl_xor(mn, 1));
        mn = fminf(mn, __shfl_xor(mn, 2));
        mn = fminf(mn, __shfl_xor(mn, 4));
        mn = fminf(mn, __shfl_xor(mn, 8));
        runmin = fminf(runmin, mn);
    };

    issueT(0, 0, buf0);
    issueT(0, 1, buf1);

#define STEP(CQ, NL, DO_ISSUE, LAST)                                             \
    {                                                                            \
        float* cur = ((CQ) & 1) ? buf1 : buf0;                                   \
        if (LAST) { asm volatile("s_waitcnt vmcnt(0)" ::: "memory"); }           \
        else      { asm volatile("s_waitcnt vmcnt(4)" ::: "memory"); }           \
        __builtin_amdgcn_sched_barrier(0);                                       \
        __builtin_amdgcn_s_barrier();                                            \
        _Pragma("unroll")                                                        \
        for (int s = 0; s < 2; ++s) {                                            \
            const int grpx = (wid * 8 + s * 4 + (c16 >> 2)) ^ ((lg & 1) << 2);   \
            const float* rp = cur + lg * 2048 + grpx * 4 + (c16 & 3);            \
            float tv[8];                                                         \
            _Pragma("unroll")                                                    \
            for (int b = 0; b < 8; ++b) tv[b] = rp[b * 256];                     \
            union { unsigned d[4]; bf16x8 v; } bb;                               \
            _Pragma("unroll")                                                    \
            for (int i = 0; i < 4; ++i) {                                        \
                unsigned r0 = __float_as_uint(tv[2 * i])     + 0x8000u;          \
                unsigned r1 = __float_as_uint(tv[2 * i + 1]) + 0x8000u;          \
                bb.d[i] = __builtin_amdgcn_perm(r1, r0, 0x07060302u);            \
            }                                                                    \
            _Pragma("unroll")                                                    \
            for (int mt = 0; mt < 8; ++mt)                                       \
                acc[s][mt] = __builtin_amdgcn_mfma_f32_16x16x32_bf16(            \
                    A[mt][(CQ)], bb.v, acc[s][mt], 0, 0, 0);                     \
        }                                                                        \
        if ((CQ) == 3) epi(NL);                                                  \
        __builtin_amdgcn_s_barrier();                                            \
        if (DO_ISSUE) issueT((NL) + ((CQ) >= 2 ? 1 : 0), ((CQ) + 2) & 3, cur);   \
    }

    for (int nl = 0; nl < 7; ++nl) {
        STEP(0, nl, true, false)
        STEP(1, nl, true, false)
        STEP(2, nl, true, false)
        STEP(3, nl, true, false)
    }
    STEP(0, 7, true,  false)
    STEP(1, 7, true,  false)
    STEP(2, 7, false, false)
    STEP(3, 7, false, true)
#undef STEP

    union { float f; unsigned u; } e; e.f = runmin;
    unsigned key = (e.u & 0x80000000u) ? ~e.u : (e.u | 0x80000000u);
    if (l == 0) atomicMin(minw, key);
}

// ---------------- tail: mask + softmax + message + mlp1 + mlp2 ----------------
// One block per 2 n-rows (grid 128). msg/hid live in LDS only.
__global__ __launch_bounds__(256) void k_tail(
    float* __restrict__ scores, const int* __restrict__ mask,
    const float* __restrict__ src, const unsigned* __restrict__ minw,
    const float* __restrict__ w3, const float* __restrict__ w4,
    const float* __restrict__ b4, const float* __restrict__ p1,
    float* __restrict__ out) {
    __shared__ float sc[2][2048];
    __shared__ float red[2][8];
    __shared__ float msgl[2][128];
    __shared__ float hidl[2][256];
    const int t = threadIdx.x, l = t & 63, wv = t >> 6;
    const int n0 = blockIdx.x * 2;

    unsigned key = *minw;
    union { float f; unsigned u; } d;
    d.u = (key & 0x80000000u) ? (key ^ 0x80000000u) : ~key;
    const float neg = d.f - 20.f;

#pragma unroll
    for (int nn = 0; nn < 2; ++nn) {
        int n = n0 + nn;
        float lmax = -1e30f;
#pragma unroll
        for (int i = 0; i < 8; ++i) {
            int m = t + i * 256;
            float v = scores[n * 2048 + m];
            if (!mask[n * 2048 + m]) v += neg;
            scores[n * 2048 + m] = v;      // final (masked) scores out
            sc[nn][m] = v;
            lmax = fmaxf(lmax, v);
        }
#pragma unroll
        for (int off = 1; off < 64; off <<= 1) lmax = fmaxf(lmax, __shfl_xor(lmax, off));
        if (l == 0) red[nn][wv] = lmax;
    }
    __syncthreads();
    float smax[2], lsum[2] = {0.f, 0.f};
#pragma unroll
    for (int nn = 0; nn < 2; ++nn)
        smax[nn] = fmaxf(fmaxf(red[nn][0], red[nn][1]), fmaxf(red[nn][2], red[nn][3]));
#pragma unroll
    for (int nn = 0; nn < 2; ++nn) {
#pragma unroll
        for (int i = 0; i < 8; ++i) {
            int m = t + i * 256;
            float e = __expf(sc[nn][m] - smax[nn]);
            sc[nn][m] = e;
            lsum[nn] += e;
        }
#pragma unroll
        for (int off = 1; off < 64; off <<= 1) lsum[nn] += __shfl_xor(lsum[nn], off);
        if (l == 0) red[nn][4 + wv] = lsum[nn];
    }
    __syncthreads();
    const float rinv0 = 1.f / (red[0][4] + red[0][5] + red[0][6] + red[0][7]);
    const float rinv1 = 1.f / (red[1][4] + red[1][5] + red[1][6] + red[1][7]);

    // message: 4 waves x 32 channels, both n share each src read
    for (int dd = 0; dd < 32; ++dd) {
        int dch = wv * 32 + dd;
        const float* sr = src + dch * 2048;
        float pa = 0.f, pb = 0.f;
#pragma unroll
        for (int j = 0; j < 32; ++j) {
            int mm = l + j * 64;
            float s = sr[mm];
            pa = fmaf(sc[0][mm], s, pa);
            pb = fmaf(sc[1][mm], s, pb);
        }
#pragma unroll
        for (int off = 1; off < 64; off <<= 1) {
            pa += __shfl_xor(pa, off);
            pb += __shfl_xor(pb, off);
        }
        if (l == 0) { msgl[0][dch] = pa * rinv0; msgl[1][dch] = pb * rinv1; }
    }
    __syncthreads();

    // hid[o] = relu(p1[o][n] + sum_c w3[o][128+c]*msg[c]),  o = t
    {
        int o = t;
        const float* wr = w3 + o * 256 + 128;
        float a0 = p1[o * 256 + n0];
        float a1 = p1[o * 256 + n0 + 1];
#pragma unroll
        for (int c = 0; c < 128; c += 4) {
            float4 w4v = *(const float4*)(wr + c);
            a0 = fmaf(w4v.x, msgl[0][c], a0);   a1 = fmaf(w4v.x, msgl[1][c], a1);
            a0 = fmaf(w4v.y, msgl[0][c + 1], a0); a1 = fmaf(w4v.y, msgl[1][c + 1], a1);
            a0 = fmaf(w4v.z, msgl[0][c + 2], a0); a1 = fmaf(w4v.z, msgl[1][c + 2], a1);
            a0 = fmaf(w4v.w, msgl[0][c + 3], a0); a1 = fmaf(w4v.w, msgl[1][c + 3], a1);
        }
        hidl[0][o] = fmaxf(a0, 0.f);
        hidl[1][o] = fmaxf(a1, 0.f);
    }
    __syncthreads();

    // out[o][n] = b4[o] + sum_c w4[o][c]*hid[c],  o = t&127, nn = t>>7
    {
        int o = t & 127, nn = t >> 7;
        const float* wr = w4 + o * 256;
        const float* hr = hidl[nn];
        float acc = b4[o];
#pragma unroll
        for (int c = 0; c < 256; c += 4) {
            float4 w4v = *(const float4*)(wr + c);
            acc = fmaf(w4v.x, hr[c], acc);
            acc = fmaf(w4v.y, hr[c + 1], acc);
            acc = fmaf(w4v.z, hr[c + 2], acc);
            acc = fmaf(w4v.w, hr[c + 3], acc);
        }
        out[o * 256 + n0 + nn] = acc;
    }
}

extern "C" void kernel_launch(void* const* d_in, const int* in_sizes, int n_in,
                              void* d_out, int out_size, void* d_ws, size_t ws_size,
                              hipStream_t stream) {
    const float* x      = (const float*)d_in[0];
    const float* source = (const float*)d_in[1];
    const float* dist   = (const float*)d_in[2];
    const int*   mask   = (const int*)d_in[3];
    const float* w1     = (const float*)d_in[4];
    const float* b1     = (const float*)d_in[5];
    const float* w2     = (const float*)d_in[6];
    const float* b2     = (const float*)d_in[7];
    const float* w3     = (const float*)d_in[8];
    const float* b3     = (const float*)d_in[9];
    const float* w4     = (const float*)d_in[10];
    const float* b4     = (const float*)d_in[11];

    float* outp    = (float*)d_out;          // 128*256
    float* scoresp = outp + 32768;           // 256*2048 (raw, then masked in-place)

    float* ws   = (float*)d_ws;
    float* qb   = ws;                 // 32768
    float* kh   = ws + 32768;         // 262144
    float* p1   = ws + 294912;        // 65536
    unsigned* minw = (unsigned*)(ws + 360448);

    k_prep<<<1408, 256, 0, stream>>>(w1, x, b1, source, w3, b3, qb, kh, p1, minw);
    k_scores<<<256, 512, 0, stream>>>(dist, w1, qb, kh, w2, b2, scoresp, minw);
    k_tail<<<128, 256, 0, stream>>>(scoresp, mask, source, minw, w3, w4, b4, p1, outp);
}